// Round 1
// baseline (5590.128 us; speedup 1.0000x reference)
//
#include <hip/hip_runtime.h>

// ---------------------------------------------------------------------------
// Swin block, fp32 correctness-first baseline.
// Pipeline:
//  K1 ln1+shift+window        x            -> Bf (windowed, TOKx384)
//  K2 gemm qkv (chunked x4)   Bf chunk     -> A  (chunk x 1152)
//  K3 attention (chunked x4)  A            -> Bf (ctx rows of chunk)
//  K4 gemm proj               Bf           -> Cf (windowed)
//  K5 unshift+residual+LN2    x, Cf        -> d_out (h), Bf (ln2)
//  K6 gemm fc1+GELU (chunk)   Bf chunk     -> A
//  K7 gemm fc2 + h (chunk)    A, d_out     -> d_out
// Workspace: A 154.2MB | Bf 154.2MB | Cf 154.2MB = 462.5MB total.
// ---------------------------------------------------------------------------

#define DIMC   384
#define HEADS  12
#define HDIM   32
#define WSZ    7
#define SHIFTS 3
#define NTOK   49
#define HID    1536
#define BATCH  32
#define HH     56
#define WW2    56
#define NW     64           // windows per image (8x8)
#define NWIN   (BATCH*NW)   // 2048
#define TOK    (NWIN*NTOK)  // 100352  == BATCH*HH*WW2
#define QKSCALE 0.17677669529663687f

#define NCHUNK 4
#define ROWS_PER_CHUNK (TOK/NCHUNK)     // 25088
#define WIN_PER_CHUNK  (NWIN/NCHUNK)    // 512

__device__ __forceinline__ float wave_sum(float v) {
#pragma unroll
  for (int o = 32; o > 0; o >>= 1) v += __shfl_xor(v, o, 64);
  return v;
}
__device__ __forceinline__ float wave_max(float v) {
#pragma unroll
  for (int o = 32; o > 0; o >>= 1) v = fmaxf(v, __shfl_xor(v, o, 64));
  return v;
}

// --------------------------- K1: LN1 + shift + window partition ------------
__global__ __launch_bounds__(256) void ln1_window_kernel(
    const float* __restrict__ x, const float* __restrict__ gamma,
    const float* __restrict__ beta, float* __restrict__ out) {
  int wave = threadIdx.x >> 6, lane = threadIdx.x & 63;
  int token = blockIdx.x * 4 + wave;            // windowed token id
  if (token >= TOK) return;
  int n  = token % NTOK;
  int b_ = token / NTOK;
  int b  = b_ >> 6;
  int w  = b_ & 63;
  int yw = (w >> 3) * WSZ + n / WSZ;            // shifted-image coords
  int xw = (w & 7) * WSZ + n % WSZ;
  int ys = yw + SHIFTS; if (ys >= HH)  ys -= HH;
  int xs = xw + SHIFTS; if (xs >= WW2) xs -= WW2;
  const float* src = x + (size_t)(b * HH * WW2 + ys * WW2 + xs) * DIMC;
  float v[6], s = 0.f, s2 = 0.f;
#pragma unroll
  for (int i = 0; i < 6; i++) {
    v[i] = src[lane + 64 * i];
    s += v[i]; s2 += v[i] * v[i];
  }
  s = wave_sum(s); s2 = wave_sum(s2);
  float mu = s * (1.f / DIMC);
  float var = s2 * (1.f / DIMC) - mu * mu;
  float r = rsqrtf(var + 1e-5f);
  float* dst = out + (size_t)token * DIMC;
#pragma unroll
  for (int i = 0; i < 6; i++) {
    int c = lane + 64 * i;
    dst[c] = (v[i] - mu) * r * gamma[c] + beta[c];
  }
}

// --------------------------- generic fp32 GEMM -----------------------------
// C[M,N] = act(A[M,K] @ B[K,N] + bias) (+ addsrc). 64x64 tile, BK=32,
// 256 threads, 4x4 per thread.
template <bool GELU_ACT, bool ADD_SRC>
__global__ __launch_bounds__(256) void gemm_kernel(
    const float* __restrict__ A, const float* __restrict__ Bm,
    const float* __restrict__ bias, const float* __restrict__ addsrc,
    float* __restrict__ C, int M, int N, int K) {
  const int BM = 64, BN = 64, BK = 32;
  __shared__ float As[BK][BM + 4];
  __shared__ float Bs[BK][BN];
  int tid = threadIdx.x;
  int tm = tid >> 4, tn = tid & 15;
  float acc[4][4] = {};
  const float* Ab = A + (size_t)blockIdx.x * BM * K;
  const float* Bb = Bm + blockIdx.y * BN;
  for (int k0 = 0; k0 < K; k0 += BK) {
#pragma unroll
    for (int it = 0; it < 2; it++) {
      int idx = tid + it * 256;
      int row = idx >> 3, c4 = idx & 7;
      float4 a = *(const float4*)(Ab + (size_t)row * K + k0 + c4 * 4);
      As[c4 * 4 + 0][row] = a.x; As[c4 * 4 + 1][row] = a.y;
      As[c4 * 4 + 2][row] = a.z; As[c4 * 4 + 3][row] = a.w;
    }
#pragma unroll
    for (int it = 0; it < 2; it++) {
      int idx = tid + it * 256;
      int row = idx >> 4, c4 = idx & 15;
      *(float4*)&Bs[row][c4 * 4] =
          *(const float4*)(Bb + (size_t)(k0 + row) * N + c4 * 4);
    }
    __syncthreads();
#pragma unroll 8
    for (int k = 0; k < BK; k++) {
      float4 a = *(const float4*)&As[k][tm * 4];
      float4 b = *(const float4*)&Bs[k][tn * 4];
      float av[4] = {a.x, a.y, a.z, a.w};
      float bv[4] = {b.x, b.y, b.z, b.w};
#pragma unroll
      for (int i = 0; i < 4; i++)
#pragma unroll
        for (int j = 0; j < 4; j++) acc[i][j] += av[i] * bv[j];
    }
    __syncthreads();
  }
  int col = blockIdx.y * BN + tn * 4;
  float4 bb = *(const float4*)&bias[col];
#pragma unroll
  for (int i = 0; i < 4; i++) {
    size_t row = (size_t)blockIdx.x * BM + tm * 4 + i;
    float4 vv = {acc[i][0] + bb.x, acc[i][1] + bb.y,
                 acc[i][2] + bb.z, acc[i][3] + bb.w};
    if (GELU_ACT) {
      vv.x = 0.5f * vv.x * (1.f + erff(vv.x * 0.70710678118f));
      vv.y = 0.5f * vv.y * (1.f + erff(vv.y * 0.70710678118f));
      vv.z = 0.5f * vv.z * (1.f + erff(vv.z * 0.70710678118f));
      vv.w = 0.5f * vv.w * (1.f + erff(vv.w * 0.70710678118f));
    }
    if (ADD_SRC) {
      float4 ad = *(const float4*)&addsrc[row * N + col];
      vv.x += ad.x; vv.y += ad.y; vv.z += ad.z; vv.w += ad.w;
    }
    *(float4*)&C[row * N + col] = vv;
  }
}

// --------------------------- K3: windowed attention ------------------------
__device__ __forceinline__ int regid(int y) { return y < 49 ? 0 : (y < 53 ? 1 : 2); }

__global__ __launch_bounds__(256) void attn_kernel(
    const float* __restrict__ qkv, const float* __restrict__ rel_table,
    float* __restrict__ ctx, int wbase) {
  __shared__ float Q[NTOK][HDIM + 4];
  __shared__ float Km[NTOK][HDIM + 4];
  __shared__ float Vm[NTOK][HDIM + 4];
  __shared__ float S[NTOK][NTOK + 1];
  __shared__ float rel_s[169];
  __shared__ int rid[NTOK];

  int bwl = blockIdx.x / HEADS;       // window within chunk
  int h   = blockIdx.x % HEADS;
  int bwg = wbase + bwl;              // global window
  int tid = threadIdx.x;

  const float* base = qkv + (size_t)bwl * NTOK * (3 * DIMC) + h * HDIM;
  for (int idx = tid; idx < NTOK * HDIM; idx += 256) {
    int n = idx >> 5, d = idx & 31;
    const float* rowp = base + (size_t)n * (3 * DIMC);
    Q[n][d]  = rowp[d] * QKSCALE;
    Km[n][d] = rowp[DIMC + d];
    Vm[n][d] = rowp[2 * DIMC + d];
  }
  for (int idx = tid; idx < 169; idx += 256) rel_s[idx] = rel_table[idx * HEADS + h];
  {
    int w = bwg & 63, wy = w >> 3, wx = w & 7;
    for (int idx = tid; idx < NTOK; idx += 256)
      rid[idx] = regid(wy * WSZ + idx / WSZ) * 3 + regid(wx * WSZ + idx % WSZ);
  }
  __syncthreads();

  // S = Q K^T + rel_bias + mask
  for (int idx = tid; idx < NTOK * NTOK; idx += 256) {
    int i = idx / NTOK, j = idx % NTOK;
    float s = 0.f;
#pragma unroll
    for (int d4 = 0; d4 < 8; d4++) {
      float4 qa = *(const float4*)&Q[i][d4 * 4];
      float4 kb = *(const float4*)&Km[j][d4 * 4];
      s += qa.x * kb.x + qa.y * kb.y + qa.z * kb.z + qa.w * kb.w;
    }
    int yi = i / WSZ, xi = i % WSZ, yj = j / WSZ, xj = j % WSZ;
    s += rel_s[(yi - yj + 6) * 13 + (xi - xj + 6)];
    if (rid[i] != rid[j]) s -= 100.f;
    S[i][j] = s;
  }
  __syncthreads();

  // row softmax: one row per wave
  int wave = tid >> 6, lane = tid & 63;
  for (int r = wave; r < NTOK; r += 4) {
    float vv = (lane < NTOK) ? S[r][lane] : -1e30f;
    float m = wave_max(vv);
    float e = (lane < NTOK) ? __expf(vv - m) : 0.f;
    float ssum = wave_sum(e);
    if (lane < NTOK) S[r][lane] = e * (1.f / ssum);
  }
  __syncthreads();

  // O = P @ V  (thread owns (row, 4 dims))
  for (int idx = tid; idx < NTOK * (HDIM / 4); idx += 256) {
    int i = idx >> 3, d4 = idx & 7;
    float4 o = {0.f, 0.f, 0.f, 0.f};
#pragma unroll 7
    for (int j = 0; j < NTOK; j++) {
      float p = S[i][j];
      float4 vv = *(const float4*)&Vm[j][d4 * 4];
      o.x += p * vv.x; o.y += p * vv.y; o.z += p * vv.z; o.w += p * vv.w;
    }
    *(float4*)&ctx[((size_t)bwg * NTOK + i) * DIMC + h * HDIM + d4 * 4] = o;
  }
}

// --------------------------- K5: unshift + residual + LN2 ------------------
__global__ __launch_bounds__(256) void unshift_ln2_kernel(
    const float* __restrict__ x, const float* __restrict__ projw,
    const float* __restrict__ gamma, const float* __restrict__ beta,
    float* __restrict__ hout, float* __restrict__ ln2) {
  int wave = threadIdx.x >> 6, lane = threadIdx.x & 63;
  int token = blockIdx.x * 4 + wave;          // image-layout token
  if (token >= TOK) return;
  int b = token / (HH * WW2);
  int yx = token % (HH * WW2);
  int y = yx / WW2, xq = yx % WW2;
  int ys = y - SHIFTS;  if (ys < 0) ys += HH;
  int xs = xq - SHIFTS; if (xs < 0) xs += WW2;
  int wtok = (b * NW + (ys / WSZ) * 8 + (xs / WSZ)) * NTOK + (ys % WSZ) * WSZ + (xs % WSZ);
  const float* xp = x + (size_t)token * DIMC;
  const float* pp = projw + (size_t)wtok * DIMC;
  float v[6], s = 0.f, s2 = 0.f;
#pragma unroll
  for (int i = 0; i < 6; i++) {
    int c = lane + 64 * i;
    float hv = xp[c] + pp[c];
    v[i] = hv; s += hv; s2 += hv * hv;
  }
  s = wave_sum(s); s2 = wave_sum(s2);
  float mu = s * (1.f / DIMC);
  float var = s2 * (1.f / DIMC) - mu * mu;
  float r = rsqrtf(var + 1e-5f);
  float* hp = hout + (size_t)token * DIMC;
  float* lp = ln2 + (size_t)token * DIMC;
#pragma unroll
  for (int i = 0; i < 6; i++) {
    int c = lane + 64 * i;
    hp[c] = v[i];
    lp[c] = (v[i] - mu) * r * gamma[c] + beta[c];
  }
}

// --------------------------- launch ----------------------------------------
extern "C" void kernel_launch(void* const* d_in, const int* in_sizes, int n_in,
                              void* d_out, int out_size, void* d_ws, size_t ws_size,
                              hipStream_t stream) {
  const float* x      = (const float*)d_in[0];
  const float* gamma1 = (const float*)d_in[1];
  const float* beta1  = (const float*)d_in[2];
  const float* w_qkv  = (const float*)d_in[3];
  const float* b_qkv  = (const float*)d_in[4];
  const float* rel_t  = (const float*)d_in[5];
  const float* w_proj = (const float*)d_in[6];
  const float* b_proj = (const float*)d_in[7];
  const float* gamma2 = (const float*)d_in[8];
  const float* beta2  = (const float*)d_in[9];
  const float* w_fc1  = (const float*)d_in[10];
  const float* b_fc1  = (const float*)d_in[11];
  const float* w_fc2  = (const float*)d_in[12];
  const float* b_fc2  = (const float*)d_in[13];

  const size_t CH_F = (size_t)ROWS_PER_CHUNK;       // 25088 rows
  float* A  = (float*)d_ws;                          // 25088*1536 floats max
  float* Bf = A  + CH_F * HID;                       // TOK*384
  float* Cf = Bf + (size_t)TOK * DIMC;               // TOK*384
  float* out = (float*)d_out;

  // K1: LN1 + shift + window partition -> Bf
  ln1_window_kernel<<<TOK / 4, 256, 0, stream>>>(x, gamma1, beta1, Bf);

  // K2/K3 chunked: qkv gemm then attention
  for (int c = 0; c < NCHUNK; c++) {
    const float* in = Bf + (size_t)c * CH_F * DIMC;
    gemm_kernel<false, false><<<dim3(ROWS_PER_CHUNK / 64, 1152 / 64), 256, 0, stream>>>(
        in, w_qkv, b_qkv, nullptr, A, ROWS_PER_CHUNK, 3 * DIMC, DIMC);
    attn_kernel<<<WIN_PER_CHUNK * HEADS, 256, 0, stream>>>(
        A, rel_t, Bf, c * WIN_PER_CHUNK);
  }

  // K4: proj gemm (windowed layout) -> Cf
  gemm_kernel<false, false><<<dim3(TOK / 64, DIMC / 64), 256, 0, stream>>>(
      Bf, w_proj, b_proj, nullptr, Cf, TOK, DIMC, DIMC);

  // K5: unshift + residual + LN2 -> d_out (h), Bf (ln2)
  unshift_ln2_kernel<<<TOK / 4, 256, 0, stream>>>(x, Cf, gamma2, beta2, out, Bf);

  // K6/K7 chunked MLP
  for (int c = 0; c < NCHUNK; c++) {
    const float* in = Bf + (size_t)c * CH_F * DIMC;
    float* hrow = out + (size_t)c * CH_F * DIMC;
    gemm_kernel<true, false><<<dim3(ROWS_PER_CHUNK / 64, HID / 64), 256, 0, stream>>>(
        in, w_fc1, b_fc1, nullptr, A, ROWS_PER_CHUNK, HID, DIMC);
    gemm_kernel<false, true><<<dim3(ROWS_PER_CHUNK / 64, DIMC / 64), 256, 0, stream>>>(
        A, w_fc2, b_fc2, hrow, hrow, ROWS_PER_CHUNK, DIMC, HID);
  }
}

// Round 5
// 1720.150 us; speedup vs baseline: 3.2498x; 3.2498x over previous
//
#include <hip/hip_runtime.h>

// ---------------------------------------------------------------------------
// Swin block, round 4 (resubmit of round-3 fix — GPU timeout): bf16 MFMA
// GEMMs (fp32 accumulate). Staging loop covers full 128x64 tile (4 iters).
// Pipeline:
//  T   transpose+cvt weights  w_*          -> wT (bf16 [N][K])
//  K1  ln1+shift+window       x            -> buf1 (bf16, windowed TOKx384)
//  K2  qkv mfma gemm (x4)     buf1 chunk   -> buf4 (fp32 chunk x 1152)
//  K3  attention (x4)         buf4         -> buf2 (bf16 ctx, windowed)
//  K4  proj mfma gemm         buf2         -> buf3 (fp32, windowed)
//  K5  unshift+residual+LN2   x, buf3      -> d_out (h fp32), buf1 (ln2 bf16)
//  K6  fc1 mfma gemm+GELU(x4) buf1 chunk   -> buf4 (bf16 chunk x 1536)
//  K7  fc2 mfma gemm+res (x4) buf4, d_out  -> d_out
// Workspace ~427 MB.
// ---------------------------------------------------------------------------

#define DIMC   384
#define HEADS  12
#define HDIM   32
#define WSZ    7
#define SHIFTS 3
#define NTOK   49
#define HID    1536
#define BATCH  32
#define HH     56
#define WW2    56
#define NW     64
#define NWIN   (BATCH*NW)   // 2048
#define TOK    (NWIN*NTOK)  // 100352
#define QKSCALE 0.17677669529663687f

#define NCHUNK 4
#define ROWS_PER_CHUNK (TOK/NCHUNK)     // 25088
#define WIN_PER_CHUNK  (NWIN/NCHUNK)    // 512

typedef short bf16x8 __attribute__((ext_vector_type(8)));
typedef float f32x4 __attribute__((ext_vector_type(4)));
typedef unsigned short ushort8_t __attribute__((ext_vector_type(8)));

__device__ __forceinline__ unsigned short f2bf(float f) {
  unsigned int u = __builtin_bit_cast(unsigned int, f);
  u += 0x7fffu + ((u >> 16) & 1u);
  return (unsigned short)(u >> 16);
}

__device__ __forceinline__ float wave_sum(float v) {
#pragma unroll
  for (int o = 32; o > 0; o >>= 1) v += __shfl_xor(v, o, 64);
  return v;
}
__device__ __forceinline__ float wave_max(float v) {
#pragma unroll
  for (int o = 32; o > 0; o >>= 1) v = fmaxf(v, __shfl_xor(v, o, 64));
  return v;
}

// --------------------------- weight transpose + bf16 cvt -------------------
__global__ __launch_bounds__(256) void transpose_cvt_kernel(
    const float* __restrict__ W, unsigned short* __restrict__ Wt, int K, int N) {
  __shared__ float t[32][33];
  int k0 = blockIdx.x * 32, n0 = blockIdx.y * 32;
  int tx = threadIdx.x & 31, ty = threadIdx.x >> 5;   // 8 rows per iter
#pragma unroll
  for (int i = 0; i < 4; i++) {
    int k = ty + i * 8;
    t[k][tx] = W[(size_t)(k0 + k) * N + n0 + tx];
  }
  __syncthreads();
#pragma unroll
  for (int i = 0; i < 4; i++) {
    int n = ty + i * 8;
    Wt[(size_t)(n0 + n) * K + k0 + tx] = f2bf(t[tx][n]);
  }
}

// --------------------------- K1: LN1 + shift + window ----------------------
__global__ __launch_bounds__(256) void ln1_window_kernel(
    const float* __restrict__ x, const float* __restrict__ gamma,
    const float* __restrict__ beta, unsigned short* __restrict__ out) {
  int wave = threadIdx.x >> 6, lane = threadIdx.x & 63;
  int token = blockIdx.x * 4 + wave;
  if (token >= TOK) return;
  int n  = token % NTOK;
  int b_ = token / NTOK;
  int b  = b_ >> 6;
  int w  = b_ & 63;
  int yw = (w >> 3) * WSZ + n / WSZ;
  int xw = (w & 7) * WSZ + n % WSZ;
  int ys = yw + SHIFTS; if (ys >= HH)  ys -= HH;
  int xs = xw + SHIFTS; if (xs >= WW2) xs -= WW2;
  const float* src = x + (size_t)(b * HH * WW2 + ys * WW2 + xs) * DIMC;
  float v[6], s = 0.f, s2 = 0.f;
#pragma unroll
  for (int i = 0; i < 6; i++) {
    v[i] = src[lane + 64 * i];
    s += v[i]; s2 += v[i] * v[i];
  }
  s = wave_sum(s); s2 = wave_sum(s2);
  float mu = s * (1.f / DIMC);
  float var = s2 * (1.f / DIMC) - mu * mu;
  float r = rsqrtf(var + 1e-5f);
  unsigned short* dst = out + (size_t)token * DIMC;
#pragma unroll
  for (int i = 0; i < 6; i++) {
    int c = lane + 64 * i;
    dst[c] = f2bf((v[i] - mu) * r * gamma[c] + beta[c]);
  }
}

// --------------------------- bf16 MFMA GEMM --------------------------------
// C[M,N] = act(A[M,K]bf16 @ Bt[N,K]bf16^T + bias) (+addsrc). 128x128 tile,
// BK=64, 256 threads (4 waves, 2x2 of 64x64), 4x4 16x16x32 frags per wave.
// M%128==0, N%128==0, K%64==0 (all shapes here satisfy this).
template <bool GELU_ACT, bool ADD_SRC, bool OUT_BF16>
__global__ __launch_bounds__(256) void gemm_bf16_kernel(
    const unsigned short* __restrict__ A, const unsigned short* __restrict__ Bt,
    const float* __restrict__ bias, const float* __restrict__ addsrc,
    void* __restrict__ C, int M, int N, int K) {
  __shared__ unsigned short As[128][72];   // 64 + 8 pad
  __shared__ unsigned short Bs[128][72];
  int tid = threadIdx.x;
  int lane = tid & 63, wid = tid >> 6;
  int wm = wid >> 1, wn = wid & 1;
  int bm0 = blockIdx.x * 128, bn0 = blockIdx.y * 128;

  f32x4 acc[4][4];
#pragma unroll
  for (int m = 0; m < 4; m++)
#pragma unroll
    for (int n = 0; n < 4; n++) acc[m][n] = (f32x4){0.f, 0.f, 0.f, 0.f};

  const unsigned short* Ab = A + (size_t)bm0 * K;
  const unsigned short* Bb = Bt + (size_t)bn0 * K;

  for (int k0 = 0; k0 < K; k0 += 64) {
    // stage A,B tiles: 128 rows x 64 cols = 1024 16B segments each
#pragma unroll
    for (int it = 0; it < 4; it++) {
      int idx = tid + it * 256;
      int row = idx >> 3, seg = idx & 7;
      *(ushort8_t*)&As[row][seg * 8] =
          *(const ushort8_t*)(Ab + (size_t)row * K + k0 + seg * 8);
      *(ushort8_t*)&Bs[row][seg * 8] =
          *(const ushort8_t*)(Bb + (size_t)row * K + k0 + seg * 8);
    }
    __syncthreads();
#pragma unroll
    for (int kk = 0; kk < 2; kk++) {
      bf16x8 af[4], bfr[4];
      int kof = kk * 32 + (lane >> 4) * 8;
#pragma unroll
      for (int m = 0; m < 4; m++)
        af[m] = *(const bf16x8*)&As[wm * 64 + m * 16 + (lane & 15)][kof];
#pragma unroll
      for (int n = 0; n < 4; n++)
        bfr[n] = *(const bf16x8*)&Bs[wn * 64 + n * 16 + (lane & 15)][kof];
#pragma unroll
      for (int m = 0; m < 4; m++)
#pragma unroll
        for (int n = 0; n < 4; n++)
          acc[m][n] = __builtin_amdgcn_mfma_f32_16x16x32_bf16(
              af[m], bfr[n], acc[m][n], 0, 0, 0);
    }
    __syncthreads();
  }

  // epilogue: C/D layout col = lane&15, row = (lane>>4)*4 + i
#pragma unroll
  for (int n = 0; n < 4; n++) {
    int col = bn0 + wn * 64 + n * 16 + (lane & 15);
    float bb = bias[col];
#pragma unroll
    for (int m = 0; m < 4; m++) {
      int rowb = bm0 + wm * 64 + m * 16 + ((lane >> 4) << 2);
#pragma unroll
      for (int i = 0; i < 4; i++) {
        float v = acc[m][n][i] + bb;
        if (GELU_ACT) v = 0.5f * v * (1.f + erff(v * 0.70710678118f));
        size_t off = (size_t)(rowb + i) * N + col;
        if (ADD_SRC) v += addsrc[off];
        if (OUT_BF16) ((unsigned short*)C)[off] = f2bf(v);
        else          ((float*)C)[off] = v;
      }
    }
  }
}

// --------------------------- K3: windowed attention ------------------------
__device__ __forceinline__ int regid(int y) { return y < 49 ? 0 : (y < 53 ? 1 : 2); }

__global__ __launch_bounds__(256) void attn_kernel(
    const float* __restrict__ qkv, const float* __restrict__ rel_table,
    unsigned short* __restrict__ ctx, int wbase) {
  __shared__ float Q[NTOK][HDIM + 4];
  __shared__ float Km[NTOK][HDIM + 4];
  __shared__ float Vm[NTOK][HDIM + 4];
  __shared__ float S[NTOK][NTOK + 1];
  __shared__ float rel_s[169];
  __shared__ int rid[NTOK];

  int bwl = blockIdx.x / HEADS;
  int h   = blockIdx.x % HEADS;
  int bwg = wbase + bwl;
  int tid = threadIdx.x;

  const float* base = qkv + (size_t)bwl * NTOK * (3 * DIMC) + h * HDIM;
  for (int idx = tid; idx < NTOK * HDIM; idx += 256) {
    int n = idx >> 5, d = idx & 31;
    const float* rowp = base + (size_t)n * (3 * DIMC);
    Q[n][d]  = rowp[d] * QKSCALE;
    Km[n][d] = rowp[DIMC + d];
    Vm[n][d] = rowp[2 * DIMC + d];
  }
  for (int idx = tid; idx < 169; idx += 256) rel_s[idx] = rel_table[idx * HEADS + h];
  {
    int w = bwg & 63, wy = w >> 3, wx = w & 7;
    for (int idx = tid; idx < NTOK; idx += 256)
      rid[idx] = regid(wy * WSZ + idx / WSZ) * 3 + regid(wx * WSZ + idx % WSZ);
  }
  __syncthreads();

  for (int idx = tid; idx < NTOK * NTOK; idx += 256) {
    int i = idx / NTOK, j = idx % NTOK;
    float s = 0.f;
#pragma unroll
    for (int d4 = 0; d4 < 8; d4++) {
      float4 qa = *(const float4*)&Q[i][d4 * 4];
      float4 kb = *(const float4*)&Km[j][d4 * 4];
      s += qa.x * kb.x + qa.y * kb.y + qa.z * kb.z + qa.w * kb.w;
    }
    int yi = i / WSZ, xi = i % WSZ, yj = j / WSZ, xj = j % WSZ;
    s += rel_s[(yi - yj + 6) * 13 + (xi - xj + 6)];
    if (rid[i] != rid[j]) s -= 100.f;
    S[i][j] = s;
  }
  __syncthreads();

  int wave = tid >> 6, lane = tid & 63;
  for (int r = wave; r < NTOK; r += 4) {
    float vv = (lane < NTOK) ? S[r][lane] : -1e30f;
    float m = wave_max(vv);
    float e = (lane < NTOK) ? __expf(vv - m) : 0.f;
    float ssum = wave_sum(e);
    if (lane < NTOK) S[r][lane] = e * (1.f / ssum);
  }
  __syncthreads();

  for (int idx = tid; idx < NTOK * (HDIM / 4); idx += 256) {
    int i = idx >> 3, d4 = idx & 7;
    float4 o = {0.f, 0.f, 0.f, 0.f};
#pragma unroll 7
    for (int j = 0; j < NTOK; j++) {
      float p = S[i][j];
      float4 vv = *(const float4*)&Vm[j][d4 * 4];
      o.x += p * vv.x; o.y += p * vv.y; o.z += p * vv.z; o.w += p * vv.w;
    }
    ushort4 o4 = {f2bf(o.x), f2bf(o.y), f2bf(o.z), f2bf(o.w)};
    *(ushort4*)&ctx[((size_t)bwg * NTOK + i) * DIMC + h * HDIM + d4 * 4] = o4;
  }
}

// --------------------------- K5: unshift + residual + LN2 ------------------
__global__ __launch_bounds__(256) void unshift_ln2_kernel(
    const float* __restrict__ x, const float* __restrict__ projw,
    const float* __restrict__ gamma, const float* __restrict__ beta,
    float* __restrict__ hout, unsigned short* __restrict__ ln2) {
  int wave = threadIdx.x >> 6, lane = threadIdx.x & 63;
  int token = blockIdx.x * 4 + wave;
  if (token >= TOK) return;
  int b = token / (HH * WW2);
  int yx = token % (HH * WW2);
  int y = yx / WW2, xq = yx % WW2;
  int ys = y - SHIFTS;  if (ys < 0) ys += HH;
  int xs = xq - SHIFTS; if (xs < 0) xs += WW2;
  int wtok = (b * NW + (ys / WSZ) * 8 + (xs / WSZ)) * NTOK + (ys % WSZ) * WSZ + (xs % WSZ);
  const float* xp = x + (size_t)token * DIMC;
  const float* pp = projw + (size_t)wtok * DIMC;
  float v[6], s = 0.f, s2 = 0.f;
#pragma unroll
  for (int i = 0; i < 6; i++) {
    int c = lane + 64 * i;
    float hv = xp[c] + pp[c];
    v[i] = hv; s += hv; s2 += hv * hv;
  }
  s = wave_sum(s); s2 = wave_sum(s2);
  float mu = s * (1.f / DIMC);
  float var = s2 * (1.f / DIMC) - mu * mu;
  float r = rsqrtf(var + 1e-5f);
  float* hp = hout + (size_t)token * DIMC;
  unsigned short* lp = ln2 + (size_t)token * DIMC;
#pragma unroll
  for (int i = 0; i < 6; i++) {
    int c = lane + 64 * i;
    hp[c] = v[i];
    lp[c] = f2bf((v[i] - mu) * r * gamma[c] + beta[c]);
  }
}

// --------------------------- launch ----------------------------------------
extern "C" void kernel_launch(void* const* d_in, const int* in_sizes, int n_in,
                              void* d_out, int out_size, void* d_ws, size_t ws_size,
                              hipStream_t stream) {
  const float* x      = (const float*)d_in[0];
  const float* gamma1 = (const float*)d_in[1];
  const float* beta1  = (const float*)d_in[2];
  const float* w_qkv  = (const float*)d_in[3];
  const float* b_qkv  = (const float*)d_in[4];
  const float* rel_t  = (const float*)d_in[5];
  const float* w_proj = (const float*)d_in[6];
  const float* b_proj = (const float*)d_in[7];
  const float* gamma2 = (const float*)d_in[8];
  const float* beta2  = (const float*)d_in[9];
  const float* w_fc1  = (const float*)d_in[10];
  const float* b_fc1  = (const float*)d_in[11];
  const float* w_fc2  = (const float*)d_in[12];
  const float* b_fc2  = (const float*)d_in[13];

  char* p = (char*)d_ws;
  unsigned short* wqkvT = (unsigned short*)p; p += (size_t)1152 * 384 * 2;
  unsigned short* wprojT = (unsigned short*)p; p += (size_t)384 * 384 * 2;
  unsigned short* wfc1T = (unsigned short*)p; p += (size_t)1536 * 384 * 2;
  unsigned short* wfc2T = (unsigned short*)p; p += (size_t)384 * 1536 * 2;
  unsigned short* buf1 = (unsigned short*)p; p += (size_t)TOK * DIMC * 2;
  unsigned short* buf2 = (unsigned short*)p; p += (size_t)TOK * DIMC * 2;
  float* buf3 = (float*)p; p += (size_t)TOK * DIMC * 4;
  float* buf4 = (float*)p;  // chunk scratch: max(25088*1152 f32, 25088*1536 bf16)
  float* out = (float*)d_out;

  // weight transpose + cvt
  transpose_cvt_kernel<<<dim3(384 / 32, 1152 / 32), 256, 0, stream>>>(w_qkv, wqkvT, 384, 1152);
  transpose_cvt_kernel<<<dim3(384 / 32, 384 / 32), 256, 0, stream>>>(w_proj, wprojT, 384, 384);
  transpose_cvt_kernel<<<dim3(384 / 32, 1536 / 32), 256, 0, stream>>>(w_fc1, wfc1T, 384, 1536);
  transpose_cvt_kernel<<<dim3(1536 / 32, 384 / 32), 256, 0, stream>>>(w_fc2, wfc2T, 1536, 384);

  // K1
  ln1_window_kernel<<<TOK / 4, 256, 0, stream>>>(x, gamma1, beta1, buf1);

  // K2/K3 chunked
  for (int c = 0; c < NCHUNK; c++) {
    const unsigned short* in = buf1 + (size_t)c * ROWS_PER_CHUNK * DIMC;
    gemm_bf16_kernel<false, false, false>
        <<<dim3(ROWS_PER_CHUNK / 128, 1152 / 128), 256, 0, stream>>>(
        in, wqkvT, b_qkv, nullptr, buf4, ROWS_PER_CHUNK, 3 * DIMC, DIMC);
    attn_kernel<<<WIN_PER_CHUNK * HEADS, 256, 0, stream>>>(
        buf4, rel_t, buf2, c * WIN_PER_CHUNK);
  }

  // K4: proj
  gemm_bf16_kernel<false, false, false>
      <<<dim3(TOK / 128, DIMC / 128), 256, 0, stream>>>(
      buf2, wprojT, b_proj, nullptr, buf3, TOK, DIMC, DIMC);

  // K5
  unshift_ln2_kernel<<<TOK / 4, 256, 0, stream>>>(x, buf3, gamma2, beta2, out, buf1);

  // K6/K7 chunked MLP
  for (int c = 0; c < NCHUNK; c++) {
    const unsigned short* in = buf1 + (size_t)c * ROWS_PER_CHUNK * DIMC;
    float* hrow = out + (size_t)c * ROWS_PER_CHUNK * DIMC;
    gemm_bf16_kernel<true, false, true>
        <<<dim3(ROWS_PER_CHUNK / 128, HID / 128), 256, 0, stream>>>(
        in, wfc1T, b_fc1, nullptr, buf4, ROWS_PER_CHUNK, HID, DIMC);
    gemm_bf16_kernel<false, true, false>
        <<<dim3(ROWS_PER_CHUNK / 128, DIMC / 128), 256, 0, stream>>>(
        (const unsigned short*)buf4, wfc2T, b_fc2, hrow, hrow, ROWS_PER_CHUNK, DIMC, HID);
  }
}